// Round 2
// baseline (425.979 us; speedup 1.0000x reference)
//
#include <hip/hip_runtime.h>
#include <hip/hip_bf16.h>
#include <hip/hip_fp16.h>

#define N_NODES 10000
#define N_EDGES 160000
#define FEAT_W 320
#define CHUNK 32

typedef _Float16 half8 __attribute__((ext_vector_type(8)));
typedef float f32x4 __attribute__((ext_vector_type(4)));

__device__ __forceinline__ float gelu_tanh(float x) {
    float x3 = x * x * x;
    float t = tanhf(0.7978845608028654f * (x + 0.044715f * x3));
    return 0.5f * x * (1.0f + t);
}

// ---------------- Kernel 1: node transforms, 8 nodes/block, fused feat+self -
__global__ __launch_bounds__(320) void node_transform(
    const float* __restrict__ node_input,
    const float* __restrict__ Wa0, const float* __restrict__ Wa1,
    const float* __restrict__ Wb0, const float* __restrict__ Wb1,
    float* __restrict__ feat_tbl, float* __restrict__ self_tbl)
{
    __shared__ __align__(16) float xT[FEAT_W][8];   // 10.24 KB
    const int node0 = blockIdx.x * 8;
    const int t = threadIdx.x;                      // 0..319 = output col
    for (int q = t; q < 640; q += 320) {            // 8 rows x 80 float4
        const int n = q / 80, c4 = q - n * 80;
        const float4 v = ((const float4*)(node_input + (size_t)(node0 + n) * FEAT_W))[c4];
        xT[c4 * 4 + 0][n] = v.x; xT[c4 * 4 + 1][n] = v.y;
        xT[c4 * 4 + 2][n] = v.z; xT[c4 * 4 + 3][n] = v.w;
    }
    __syncthreads();

    float accf[8] = {0,0,0,0,0,0,0,0}, accs[8] = {0,0,0,0,0,0,0,0};
    float scale;
    if (t < 128) {
        for (int v = 0; v < 128; ++v) {
            const float wa = Wa0[v * 128 + t];
            const float wb = Wb0[v * 128 + t];
            const float4 xa = *(const float4*)&xT[v][0];
            const float4 xb = *(const float4*)&xT[v][4];
            accf[0] += xa.x * wa; accf[1] += xa.y * wa; accf[2] += xa.z * wa; accf[3] += xa.w * wa;
            accf[4] += xb.x * wa; accf[5] += xb.y * wa; accf[6] += xb.z * wa; accf[7] += xb.w * wa;
            accs[0] += xa.x * wb; accs[1] += xa.y * wb; accs[2] += xa.z * wb; accs[3] += xa.w * wb;
            accs[4] += xb.x * wb; accs[5] += xb.y * wb; accs[6] += xb.z * wb; accs[7] += xb.w * wb;
        }
        scale = 0.08838834764831845f;               // 1/sqrt(128)
    } else {
        const int r = t - 128, u = r / 3, i = r - 3 * u;
        for (int v = 0; v < 64; ++v) {
            const float wa = Wa1[v * 64 + u];
            const float wb = Wb1[v * 64 + u];
            const int row = 128 + v * 3 + i;
            const float4 xa = *(const float4*)&xT[row][0];
            const float4 xb = *(const float4*)&xT[row][4];
            accf[0] += xa.x * wa; accf[1] += xa.y * wa; accf[2] += xa.z * wa; accf[3] += xa.w * wa;
            accf[4] += xb.x * wa; accf[5] += xb.y * wa; accf[6] += xb.z * wa; accf[7] += xb.w * wa;
            accs[0] += xa.x * wb; accs[1] += xa.y * wb; accs[2] += xa.z * wb; accs[3] += xa.w * wb;
            accs[4] += xb.x * wb; accs[5] += xb.y * wb; accs[6] += xb.z * wb; accs[7] += xb.w * wb;
        }
        scale = 0.125f;                             // 1/sqrt(64)
    }
#pragma unroll
    for (int n = 0; n < 8; ++n) {
        feat_tbl[(size_t)(node0 + n) * FEAT_W + t] = accf[n] * scale;
        self_tbl[(size_t)(node0 + n) * FEAT_W + t] = accs[n] * scale;
    }
}

// ---------------- count kernel (degrees) ------------------------------------
__global__ __launch_bounds__(256) void count_kernel(
    const int* __restrict__ edge_dst, int* __restrict__ counts)
{
    const int e = blockIdx.x * 256 + threadIdx.x;
    if (e < N_EDGES) atomicAdd(&counts[edge_dst[e]], 1);
}

// ---------------- CSR scan --------------------------------------------------
__global__ __launch_bounds__(1024) void scan_kernel(
    const int* __restrict__ counts, int* __restrict__ offsets, int* __restrict__ cursor)
{
    __shared__ int wsum[16];
    const int wid = threadIdx.x >> 6, lane = threadIdx.x & 63;
    int base = 0;
    for (int c = 0; c < 10; ++c) {            // 10*1024 >= 10000
        const int i = c * 1024 + threadIdx.x;
        const int v = (i < N_NODES) ? counts[i] : 0;
        int x = v;
#pragma unroll
        for (int off = 1; off < 64; off <<= 1) {
            int y = __shfl_up(x, off, 64);
            if (lane >= off) x += y;
        }
        if (lane == 63) wsum[wid] = x;
        __syncthreads();
        if (threadIdx.x < 16) {
            int s = wsum[threadIdx.x];
#pragma unroll
            for (int off = 1; off < 16; off <<= 1) {
                int y = __shfl_up(s, off, 64);
                if ((int)threadIdx.x >= off) s += y;
            }
            wsum[threadIdx.x] = s;
        }
        __syncthreads();
        const int waveoff = (wid == 0) ? 0 : wsum[wid - 1];
        const int excl = base + waveoff + x - v;
        if (i < N_NODES) { offsets[i] = excl; cursor[i] = excl; }
        const int tot = wsum[15];
        __syncthreads();
        base += tot;
    }
    if (threadIdx.x == 0) offsets[N_NODES] = base;
}

// fill: emits CSR-permuted src + y4 AND the edge->CSR-position map, so mlp
// can write h2 directly in CSR order (gather then streams it, no indirection).
__global__ void fill_kernel(const int* __restrict__ edge_dst,
                            const int* __restrict__ edge_src,
                            const float* __restrict__ edge_attr,
                            int* __restrict__ cursor,
                            int* __restrict__ srcs_csr, float* __restrict__ y4csr,
                            int* __restrict__ pos_csr) {
    int e = blockIdx.x * 256 + threadIdx.x;
    if (e < N_EDGES) {
        int pos = atomicAdd(&cursor[edge_dst[e]], 1);
        srcs_csr[pos] = edge_src[e];
        ((float4*)y4csr)[pos] = ((const float4*)edge_attr)[e];
        pos_csr[e] = pos;
    }
}

// ---------------- Kernel 2: per-edge MLP -> h2 f16, written in CSR order ----
// h2 pre-scaled by 1/sqrt(64) (the W-projection scale); same f16 quantization
// point as before.
__global__ __launch_bounds__(256) void mlp_kernel(
    const float* __restrict__ esa,   // (E,8)
    const float* __restrict__ M1,    // (8,64)
    const float* __restrict__ M2,    // (64,64)
    const int* __restrict__ pos_csr,
    __half* __restrict__ h2csr)      // (E,64) f16, CSR order, pre-scaled 1/8
{
    __shared__ __align__(16) float sh[4][64];
    const int wave = threadIdx.x >> 6;
    const int lane = threadIdx.x & 63;
    const int e = blockIdx.x * 4 + wave;   // N_EDGES % 4 == 0

    const int pos = pos_csr[e];            // issued early, latency hidden

    const float4 e0 = ((const float4*)(esa + (size_t)e * 8))[0];
    const float4 e1 = ((const float4*)(esa + (size_t)e * 8))[1];
    float h = e0.x * M1[0 * 64 + lane] + e0.y * M1[1 * 64 + lane]
            + e0.z * M1[2 * 64 + lane] + e0.w * M1[3 * 64 + lane]
            + e1.x * M1[4 * 64 + lane] + e1.y * M1[5 * 64 + lane]
            + e1.z * M1[6 * 64 + lane] + e1.w * M1[7 * 64 + lane];
    h = gelu_tanh(h * 0.35355339059327373f);   // 1/sqrt(8)
    sh[wave][lane] = h;
    __syncthreads();

    float h2 = 0.f;
    const float4* shp = (const float4*)sh[wave];
#pragma unroll
    for (int q = 0; q < 16; ++q) {
        const float4 s = shp[q];
        h2 += s.x * M2[(4 * q + 0) * 64 + lane];
        h2 += s.y * M2[(4 * q + 1) * 64 + lane];
        h2 += s.z * M2[(4 * q + 2) * 64 + lane];
        h2 += s.w * M2[(4 * q + 3) * 64 + lane];
    }
    h2 = gelu_tanh(h2 * 0.125f);               // 1/sqrt(64)
    h2csr[(size_t)pos * 64 + lane] = (__half)(h2 * 0.125f);  // fold 1/sqrt(64)
}

// ---------------- weight pre-pack (one-shot) --------------------------------
// gid < 1536: Wtp0..3 -> MFMA B-fragment order f16.
// gid >= 1536: Wo0/Wo1 -> f16 row-major (same indexing as f32 originals).
__global__ __launch_bounds__(256) void pack_weights(
    const float* __restrict__ Wtp0, const float* __restrict__ Wtp1,
    const float* __restrict__ Wtp2, const float* __restrict__ Wtp3,
    const float* __restrict__ Wo0,  const float* __restrict__ Wo1,
    __half* __restrict__ wtp_pack, __half* __restrict__ wo_pack)
{
    const int gid = blockIdx.x * 256 + threadIdx.x;   // 150*256 = 38400
    if (gid < 1536) {                                 // 24 tiles * 64 lanes
        const int lane = gid & 63;
        const int tile = gid >> 6;
        const int quad = lane >> 4, n16 = lane & 15;
        const int col = tile * 16 + n16;
        const float* src; int stride;
        if (col < 128)      { src = Wtp0 + col;         stride = 128; }
        else if (col < 256) { src = Wtp1 + (col - 128); stride = 128; }
        else if (col < 320) { src = Wtp2 + (col - 256); stride = 64;  }
        else                { src = Wtp3 + (col - 320); stride = 64;  }
        __half* dst = wtp_pack + (size_t)gid * 16;
#pragma unroll
        for (int s = 0; s < 2; ++s)
#pragma unroll
            for (int j = 0; j < 8; ++j)
                dst[s * 8 + j] = (__half)src[(s * 32 + quad * 8 + j) * stride];
    } else {
        const int i = gid - 1536;                     // 36864 = 192*128 + 192*64
        if (i < 24576) wo_pack[i] = (__half)Wo0[i];
        else           wo_pack[i] = (__half)Wo1[i - 24576];
    }
}

// ---------------- Kernel 3: fused W-proj (MFMA) + gather + out-GEMM ---------
// 384 threads = 6 waves, one block per node. CSR-ordered h2 -> staging is a
// pure streaming load, register-prefetched (T14): chunk-0 loads issued as the
// FIRST instructions; chunk k+1 loads issued between MFMA and the mid loop.
// wsh rows XOR-swizzled (byte ^= quad<<5 == ((row>>2)&3)<<5): conflict-free
// for both the MFMA-epilogue scalar writes and the mid-loop reads.
// z unions with h2s (z only live after the last h2s read) -> 29.3 KB LDS.
__global__ __launch_bounds__(384, 7) void gather_kernel(
    const int* __restrict__ offsets,
    const int* __restrict__ srcs_csr,
    const float* __restrict__ y4csr,
    const __half* __restrict__ h2csr,      // (E,64) f16, CSR order, pre-scaled
    const __half* __restrict__ wtp_pack,   // B-fragment packed Wtp
    const float* __restrict__ feat_tbl,    // (N,320)
    const float* __restrict__ self_tbl,    // (N,320)
    const __half* __restrict__ wo_pack,    // f16 Wo0 (192x128) ++ Wo1 (192x64)
    float* __restrict__ out)               // (N,320)
{
    __shared__ __align__(16) __half wsh[CHUNK * 384];  // 24 KB
    __shared__ __align__(16) char pool[CHUNK * 128];   // 4 KB: h2s ∪ z
    __shared__ float ys[CHUNK][4];
    __shared__ int   srcs[CHUNK];
    __half* h2s = (__half*)pool;
    float*  z   = (float*)pool;                        // 768 floats, fits

    const int node = blockIdx.x;
    const int t = threadIdx.x;             // 0..383
    const int wave = t >> 6, lane = t & 63;
    const int quad = lane >> 4, n16 = lane & 15;

    const int beg = offsets[node], end = offsets[node + 1];

    // ---- prologue: issue chunk-0 staged loads immediately (longest chain) --
    int cb = beg;
    int ne = min(CHUNK, end - cb);
    half8 hreg = {};
    int   sreg = 0;
    float4 yreg = {0.f, 0.f, 0.f, 0.f};
    if (t < ne * 8) hreg = ((const half8*)(h2csr + (size_t)cb * 64))[t];
    if (t < ne)     { sreg = srcs_csr[cb + t]; yreg = ((const float4*)y4csr)[cb + t]; }

    // ---- B fragments (L2-hot, overlap the streaming loads above) ----
    half8 bf[4][2];
#pragma unroll
    for (int c = 0; c < 4; ++c) {
        const __half* p = wtp_pack + (size_t)((wave * 4 + c) * 64 + lane) * 16;
        bf[c][0] = *(const half8*)p;
        bf[c][1] = *(const half8*)(p + 8);
    }

    int f0;
    if (t < 128)      f0 = t;
    else if (t < 256) f0 = t - 128;
    else if (t < 320) f0 = 128 + 3 * (t - 256);
    else              f0 = 128 + 3 * (t - 320);

    float acc = 0.f, acc3a = 0.f, acc3b = 0.f, acc3c = 0.f;

    for (;;) {
        // ---- commit staged regs -> LDS ----
        if (t < ne) { srcs[t] = sreg; ((float4*)ys)[t] = yreg; }
        if (t < ne * 8) {                              // <=256 units, 1/thread
            const int eL = t >> 3, u = t & 7;
            *(half8*)((char*)h2s + eL * 128 + ((u * 16) ^ ((eL & 7) << 4))) = hreg;
        }
        __syncthreads();

        // ---- W = h2 @ Wtp via MFMA -> wsh (swizzled) ----
#pragma unroll
        for (int g = 0; g < 2; ++g) {
            if (g * 16 < ne) {                         // rows >= ne never read
                const int e = g * 16 + n16;
                const char* hb = (const char*)h2s + e * 128;
                const int sw = (e & 7) << 4;
                const half8 af0 = *(const half8*)(hb + ((quad * 16) ^ sw));
                const half8 af1 = *(const half8*)(hb + ((64 + quad * 16) ^ sw));
#pragma unroll
                for (int c = 0; c < 4; ++c) {
                    f32x4 acc4 = {0.f, 0.f, 0.f, 0.f};
                    acc4 = __builtin_amdgcn_mfma_f32_16x16x32_f16(af0, bf[c][0], acc4, 0, 0, 0);
                    acc4 = __builtin_amdgcn_mfma_f32_16x16x32_f16(af1, bf[c][1], acc4, 0, 0, 0);
                    const int colb = ((wave * 4 + c) * 16 + n16) * 2;
#pragma unroll
                    for (int r = 0; r < 4; ++r) {
                        const int row = g * 16 + quad * 4 + r;
                        *(__half*)((char*)wsh + row * 768 + (colb ^ (quad << 5))) =
                            (__half)acc4[r];
                    }
                }
            }
        }

        // ---- issue next-chunk staged loads (latency hidden under mid) ----
        const int cb2 = cb + CHUNK;
        const int ne2 = (cb2 < end) ? min(CHUNK, end - cb2) : 0;
        if (t < ne2 * 8) hreg = ((const half8*)(h2csr + (size_t)cb2 * 64))[t];
        if (t < ne2)     { sreg = srcs_csr[cb2 + t]; yreg = ((const float4*)y4csr)[cb2 + t]; }
        __syncthreads();   // wsh ready

        // ---- mid / aggregation (reads wsh with the row XOR) ----
        const int tb = t * 2;
        if (t < 128) {                       // A: mid0a
            for (int e = 0; e < ne; ++e) {
                const float w = __half2float(*(const __half*)(
                    (const char*)wsh + e * 768 + (tb ^ (((e >> 2) & 3) << 5))));
                const float* fr = feat_tbl + (size_t)srcs[e] * FEAT_W;
                acc += w * fr[f0] * ys[e][0];
            }
        } else if (t < 256) {                // B: mid1a
            for (int e = 0; e < ne; ++e) {
                const float w = __half2float(*(const __half*)(
                    (const char*)wsh + e * 768 + (tb ^ (((e >> 2) & 3) << 5))));
                const float* fr = feat_tbl + (size_t)srcs[e] * FEAT_W;
                const float p = w * fr[f0];
                acc3a += p * ys[e][1];
                acc3b += p * ys[e][2];
                acc3c += p * ys[e][3];
            }
        } else if (t < 320) {                // C: mid1b
            for (int e = 0; e < ne; ++e) {
                const float w = __half2float(*(const __half*)(
                    (const char*)wsh + e * 768 + (tb ^ (((e >> 2) & 3) << 5))));
                const float* fr = feat_tbl + (size_t)srcs[e] * FEAT_W;
                const float p = w * ys[e][0];
                acc3a += p * fr[f0];
                acc3b += p * fr[f0 + 1];
                acc3c += p * fr[f0 + 2];
            }
        } else {                             // D: mid0b
            for (int e = 0; e < ne; ++e) {
                const float w = __half2float(*(const __half*)(
                    (const char*)wsh + e * 768 + (tb ^ (((e >> 2) & 3) << 5))));
                const float* fr = feat_tbl + (size_t)srcs[e] * FEAT_W;
                const float d = fr[f0] * ys[e][1] + fr[f0 + 1] * ys[e][2]
                              + fr[f0 + 2] * ys[e][3];
                acc += w * d;
            }
        }

        if (!ne2) break;
        cb = cb2; ne = ne2;
        __syncthreads();   // protect wsh/h2s/srcs before overwrite
    }

    // ---- write z (aliases h2s; last h2s read was pre-mid-barrier) ----
    const float sZ = 0.25f;                  // 1/sqrt(16)
    if (t < 128) {
        z[t] = acc * sZ;
    } else if (t < 256) {
        const int u = t - 128;
        z[192 + 0 * 192 + u] = acc3a * sZ;
        z[192 + 1 * 192 + u] = acc3b * sZ;
        z[192 + 2 * 192 + u] = acc3c * sZ;
    } else if (t < 320) {
        const int u = t - 256;
        z[192 + 0 * 192 + 128 + u] = acc3a * sZ;
        z[192 + 1 * 192 + 128 + u] = acc3b * sZ;
        z[192 + 2 * 192 + 128 + u] = acc3c * sZ;
    } else {
        z[128 + (t - 320)] = acc * sZ * 0.5773502691896258f;  // mid0b, 1/sqrt(3)
    }
    __syncthreads();

    // ---- output GEMM (f16 Wo) + rotation combine ----
    const float sA = 0.07216878364870323f;   // 1/sqrt(192)
    const float cR = 0.92387953251128674f;   // cos(pi/8)
    const float sR = 0.38268343236508978f;   // sin(pi/8)
    const __half* Wo0h = wo_pack;            // 192x128
    const __half* Wo1h = wo_pack + 24576;    // 192x64

    if (t < 128) {
        float conv = 0.f;
        const float4* z4 = (const float4*)z;
#pragma unroll 8
        for (int q = 0; q < 48; ++q) {
            const float4 zz = z4[q];
            conv += zz.x * (float)Wo0h[(4 * q + 0) * 128 + t];
            conv += zz.y * (float)Wo0h[(4 * q + 1) * 128 + t];
            conv += zz.z * (float)Wo0h[(4 * q + 2) * 128 + t];
            conv += zz.w * (float)Wo0h[(4 * q + 3) * 128 + t];
        }
        const float sv = self_tbl[(size_t)node * FEAT_W + t];
        out[(size_t)node * FEAT_W + t] = cR * sv + sR * conv * sA;
    } else if (t < 320) {
        const int idx = t - 128;
        const int i = idx >> 6, u = idx & 63;
        float conv = 0.f;
        const float4* z4 = (const float4*)(z + 192 + i * 192);
#pragma unroll 8
        for (int q = 0; q < 48; ++q) {
            const float4 zz = z4[q];
            conv += zz.x * (float)Wo1h[(4 * q + 0) * 64 + u];
            conv += zz.y * (float)Wo1h[(4 * q + 1) * 64 + u];
            conv += zz.z * (float)Wo1h[(4 * q + 2) * 64 + u];
            conv += zz.w * (float)Wo1h[(4 * q + 3) * 64 + u];
        }
        const int col = 128 + u * 3 + i;
        const float sv = self_tbl[(size_t)node * FEAT_W + col];
        out[(size_t)node * FEAT_W + col] = cR * sv + sR * conv * sA;
    }
}

extern "C" void kernel_launch(void* const* d_in, const int* in_sizes, int n_in,
                              void* d_out, int out_size, void* d_ws, size_t ws_size,
                              hipStream_t stream) {
    const float* node_input = (const float*)d_in[0];
    const float* edge_attr  = (const float*)d_in[1];
    const float* esa        = (const float*)d_in[2];
    const float* Wa0  = (const float*)d_in[3];
    const float* Wa1  = (const float*)d_in[4];
    const float* Wb0  = (const float*)d_in[5];
    const float* Wb1  = (const float*)d_in[6];
    const float* M1   = (const float*)d_in[7];
    const float* M2   = (const float*)d_in[8];
    const float* Wtp0 = (const float*)d_in[9];
    const float* Wtp1 = (const float*)d_in[10];
    const float* Wtp2 = (const float*)d_in[11];
    const float* Wtp3 = (const float*)d_in[12];
    const float* Wo0  = (const float*)d_in[13];
    const float* Wo1  = (const float*)d_in[14];
    const int* edge_src = (const int*)d_in[15];
    const int* edge_dst = (const int*)d_in[16];
    float* out = (float*)d_out;

    // ws layout (~46 MB), 16B-aligned segments
    char* w = (char*)d_ws;
    float*  feat_tbl = (float*)w;           w += (size_t)N_NODES * FEAT_W * 4;
    float*  self_tbl = (float*)w;           w += (size_t)N_NODES * FEAT_W * 4;
    float*  y4csr    = (float*)w;           w += (size_t)N_EDGES * 4 * 4;
    __half* h2csr    = (__half*)w;          w += (size_t)N_EDGES * 64 * 2;
    __half* wtp_pack = (__half*)w;          w += (size_t)24576 * 2;
    __half* wo_pack  = (__half*)w;          w += (size_t)36864 * 2;
    int*    counts   = (int*)w;             w += (size_t)N_NODES * 4;
    int*    offsets  = (int*)w;             w += (size_t)(N_NODES + 1) * 4;
    int*    cursor   = (int*)w;             w += (size_t)N_NODES * 4;
    int*    srcs_csr = (int*)w;             w += (size_t)N_EDGES * 4;
    int*    pos_csr  = (int*)w;             w += (size_t)N_EDGES * 4;

    hipMemsetAsync(counts, 0, sizeof(int) * N_NODES, stream);

    count_kernel<<<N_EDGES / 256, 256, 0, stream>>>(edge_dst, counts);
    scan_kernel<<<1, 1024, 0, stream>>>(counts, offsets, cursor);
    fill_kernel<<<N_EDGES / 256, 256, 0, stream>>>(edge_dst, edge_src, edge_attr,
                                                   cursor, srcs_csr, y4csr, pos_csr);
    pack_weights<<<150, 256, 0, stream>>>(Wtp0, Wtp1, Wtp2, Wtp3, Wo0, Wo1,
                                          wtp_pack, wo_pack);
    node_transform<<<N_NODES / 8, 320, 0, stream>>>(node_input, Wa0, Wa1, Wb0, Wb1,
                                                    feat_tbl, self_tbl);
    mlp_kernel<<<N_EDGES / 4, 256, 0, stream>>>(esa, M1, M2, pos_csr, h2csr);
    gather_kernel<<<N_NODES, 384, 0, stream>>>(offsets, srcs_csr, y4csr, h2csr,
                                               wtp_pack, feat_tbl, self_tbl,
                                               wo_pack, out);
}

// Round 3
// 408.057 us; speedup vs baseline: 1.0439x; 1.0439x over previous
//
#include <hip/hip_runtime.h>
#include <hip/hip_bf16.h>
#include <hip/hip_fp16.h>

#define N_NODES 10000
#define N_EDGES 160000
#define FEAT_W 320
#define CHUNK 32

typedef _Float16 half8 __attribute__((ext_vector_type(8)));
typedef float f32x4 __attribute__((ext_vector_type(4)));

__device__ __forceinline__ float gelu_tanh(float x) {
    float x3 = x * x * x;
    float t = tanhf(0.7978845608028654f * (x + 0.044715f * x3));
    return 0.5f * x * (1.0f + t);
}

// ---------------- Kernel 1: node transforms, 8 nodes/block, fused feat+self -
__global__ __launch_bounds__(320) void node_transform(
    const float* __restrict__ node_input,
    const float* __restrict__ Wa0, const float* __restrict__ Wa1,
    const float* __restrict__ Wb0, const float* __restrict__ Wb1,
    float* __restrict__ feat_tbl, float* __restrict__ self_tbl)
{
    __shared__ __align__(16) float xT[FEAT_W][8];   // 10.24 KB
    const int node0 = blockIdx.x * 8;
    const int t = threadIdx.x;                      // 0..319 = output col
    for (int q = t; q < 640; q += 320) {            // 8 rows x 80 float4
        const int n = q / 80, c4 = q - n * 80;
        const float4 v = ((const float4*)(node_input + (size_t)(node0 + n) * FEAT_W))[c4];
        xT[c4 * 4 + 0][n] = v.x; xT[c4 * 4 + 1][n] = v.y;
        xT[c4 * 4 + 2][n] = v.z; xT[c4 * 4 + 3][n] = v.w;
    }
    __syncthreads();

    float accf[8] = {0,0,0,0,0,0,0,0}, accs[8] = {0,0,0,0,0,0,0,0};
    float scale;
    if (t < 128) {
        for (int v = 0; v < 128; ++v) {
            const float wa = Wa0[v * 128 + t];
            const float wb = Wb0[v * 128 + t];
            const float4 xa = *(const float4*)&xT[v][0];
            const float4 xb = *(const float4*)&xT[v][4];
            accf[0] += xa.x * wa; accf[1] += xa.y * wa; accf[2] += xa.z * wa; accf[3] += xa.w * wa;
            accf[4] += xb.x * wa; accf[5] += xb.y * wa; accf[6] += xb.z * wa; accf[7] += xb.w * wa;
            accs[0] += xa.x * wb; accs[1] += xa.y * wb; accs[2] += xa.z * wb; accs[3] += xa.w * wb;
            accs[4] += xb.x * wb; accs[5] += xb.y * wb; accs[6] += xb.z * wb; accs[7] += xb.w * wb;
        }
        scale = 0.08838834764831845f;               // 1/sqrt(128)
    } else {
        const int r = t - 128, u = r / 3, i = r - 3 * u;
        for (int v = 0; v < 64; ++v) {
            const float wa = Wa1[v * 64 + u];
            const float wb = Wb1[v * 64 + u];
            const int row = 128 + v * 3 + i;
            const float4 xa = *(const float4*)&xT[row][0];
            const float4 xb = *(const float4*)&xT[row][4];
            accf[0] += xa.x * wa; accf[1] += xa.y * wa; accf[2] += xa.z * wa; accf[3] += xa.w * wa;
            accf[4] += xb.x * wa; accf[5] += xb.y * wa; accf[6] += xb.z * wa; accf[7] += xb.w * wa;
            accs[0] += xa.x * wb; accs[1] += xa.y * wb; accs[2] += xa.z * wb; accs[3] += xa.w * wb;
            accs[4] += xb.x * wb; accs[5] += xb.y * wb; accs[6] += xb.z * wb; accs[7] += xb.w * wb;
        }
        scale = 0.125f;                             // 1/sqrt(64)
    }
#pragma unroll
    for (int n = 0; n < 8; ++n) {
        feat_tbl[(size_t)(node0 + n) * FEAT_W + t] = accf[n] * scale;
        self_tbl[(size_t)(node0 + n) * FEAT_W + t] = accs[n] * scale;
    }
}

// ---------------- count kernel (degrees) ------------------------------------
__global__ __launch_bounds__(256) void count_kernel(
    const int* __restrict__ edge_dst, int* __restrict__ counts)
{
    const int e = blockIdx.x * 256 + threadIdx.x;
    if (e < N_EDGES) atomicAdd(&counts[edge_dst[e]], 1);
}

// ---------------- CSR scan --------------------------------------------------
__global__ __launch_bounds__(1024) void scan_kernel(
    const int* __restrict__ counts, int* __restrict__ offsets, int* __restrict__ cursor)
{
    __shared__ int wsum[16];
    const int wid = threadIdx.x >> 6, lane = threadIdx.x & 63;
    int base = 0;
    for (int c = 0; c < 10; ++c) {            // 10*1024 >= 10000
        const int i = c * 1024 + threadIdx.x;
        const int v = (i < N_NODES) ? counts[i] : 0;
        int x = v;
#pragma unroll
        for (int off = 1; off < 64; off <<= 1) {
            int y = __shfl_up(x, off, 64);
            if (lane >= off) x += y;
        }
        if (lane == 63) wsum[wid] = x;
        __syncthreads();
        if (threadIdx.x < 16) {
            int s = wsum[threadIdx.x];
#pragma unroll
            for (int off = 1; off < 16; off <<= 1) {
                int y = __shfl_up(s, off, 64);
                if ((int)threadIdx.x >= off) s += y;
            }
            wsum[threadIdx.x] = s;
        }
        __syncthreads();
        const int waveoff = (wid == 0) ? 0 : wsum[wid - 1];
        const int excl = base + waveoff + x - v;
        if (i < N_NODES) { offsets[i] = excl; cursor[i] = excl; }
        const int tot = wsum[15];
        __syncthreads();
        base += tot;
    }
    if (threadIdx.x == 0) offsets[N_NODES] = base;
}

// fill: emits CSR-permuted src + y4 AND the edge->CSR-position map, so mlp
// can write h2 directly in CSR order (gather then streams it, no indirection).
__global__ void fill_kernel(const int* __restrict__ edge_dst,
                            const int* __restrict__ edge_src,
                            const float* __restrict__ edge_attr,
                            int* __restrict__ cursor,
                            int* __restrict__ srcs_csr, float* __restrict__ y4csr,
                            int* __restrict__ pos_csr) {
    int e = blockIdx.x * 256 + threadIdx.x;
    if (e < N_EDGES) {
        int pos = atomicAdd(&cursor[edge_dst[e]], 1);
        srcs_csr[pos] = edge_src[e];
        ((float4*)y4csr)[pos] = ((const float4*)edge_attr)[e];
        pos_csr[e] = pos;
    }
}

// ---------------- Kernel 2: per-edge MLP -> h2 f16, written in CSR order ----
// h2 pre-scaled by 1/sqrt(64) (the W-projection scale); same f16 quantization
// point as before.
__global__ __launch_bounds__(256) void mlp_kernel(
    const float* __restrict__ esa,   // (E,8)
    const float* __restrict__ M1,    // (8,64)
    const float* __restrict__ M2,    // (64,64)
    const int* __restrict__ pos_csr,
    __half* __restrict__ h2csr)      // (E,64) f16, CSR order, pre-scaled 1/8
{
    __shared__ __align__(16) float sh[4][64];
    const int wave = threadIdx.x >> 6;
    const int lane = threadIdx.x & 63;
    const int e = blockIdx.x * 4 + wave;   // N_EDGES % 4 == 0

    const int pos = pos_csr[e];            // issued early, latency hidden

    const float4 e0 = ((const float4*)(esa + (size_t)e * 8))[0];
    const float4 e1 = ((const float4*)(esa + (size_t)e * 8))[1];
    float h = e0.x * M1[0 * 64 + lane] + e0.y * M1[1 * 64 + lane]
            + e0.z * M1[2 * 64 + lane] + e0.w * M1[3 * 64 + lane]
            + e1.x * M1[4 * 64 + lane] + e1.y * M1[5 * 64 + lane]
            + e1.z * M1[6 * 64 + lane] + e1.w * M1[7 * 64 + lane];
    h = gelu_tanh(h * 0.35355339059327373f);   // 1/sqrt(8)
    sh[wave][lane] = h;
    __syncthreads();

    float h2 = 0.f;
    const float4* shp = (const float4*)sh[wave];
#pragma unroll
    for (int q = 0; q < 16; ++q) {
        const float4 s = shp[q];
        h2 += s.x * M2[(4 * q + 0) * 64 + lane];
        h2 += s.y * M2[(4 * q + 1) * 64 + lane];
        h2 += s.z * M2[(4 * q + 2) * 64 + lane];
        h2 += s.w * M2[(4 * q + 3) * 64 + lane];
    }
    h2 = gelu_tanh(h2 * 0.125f);               // 1/sqrt(64)
    h2csr[(size_t)pos * 64 + lane] = (__half)(h2 * 0.125f);  // fold 1/sqrt(64)
}

// ---------------- weight pre-pack (one-shot) --------------------------------
// gid < 1536: Wtp0..3 -> MFMA B-fragment order f16.
// gid >= 1536: Wo0/Wo1 -> f16 row-major (same indexing as f32 originals).
__global__ __launch_bounds__(256) void pack_weights(
    const float* __restrict__ Wtp0, const float* __restrict__ Wtp1,
    const float* __restrict__ Wtp2, const float* __restrict__ Wtp3,
    const float* __restrict__ Wo0,  const float* __restrict__ Wo1,
    __half* __restrict__ wtp_pack, __half* __restrict__ wo_pack)
{
    const int gid = blockIdx.x * 256 + threadIdx.x;   // 150*256 = 38400
    if (gid < 1536) {                                 // 24 tiles * 64 lanes
        const int lane = gid & 63;
        const int tile = gid >> 6;
        const int quad = lane >> 4, n16 = lane & 15;
        const int col = tile * 16 + n16;
        const float* src; int stride;
        if (col < 128)      { src = Wtp0 + col;         stride = 128; }
        else if (col < 256) { src = Wtp1 + (col - 128); stride = 128; }
        else if (col < 320) { src = Wtp2 + (col - 256); stride = 64;  }
        else                { src = Wtp3 + (col - 320); stride = 64;  }
        __half* dst = wtp_pack + (size_t)gid * 16;
#pragma unroll
        for (int s = 0; s < 2; ++s)
#pragma unroll
            for (int j = 0; j < 8; ++j)
                dst[s * 8 + j] = (__half)src[(s * 32 + quad * 8 + j) * stride];
    } else {
        const int i = gid - 1536;                     // 36864 = 192*128 + 192*64
        if (i < 24576) wo_pack[i] = (__half)Wo0[i];
        else           wo_pack[i] = (__half)Wo1[i - 24576];
    }
}

// ---------------- Kernel 3: fused W-proj (MFMA) + gather + out-GEMM ---------
// 384 threads = 6 waves, one block per node. CSR-ordered h2 -> staging is a
// pure streaming load, register-prefetched (T14): chunk-0 loads issued as the
// FIRST instructions; chunk k+1 loads issued between MFMA and the mid loop.
// wsh rows XOR-swizzled (byte ^= quad<<5 == ((row>>2)&3)<<5): conflict-free
// for both the MFMA-epilogue scalar writes and the mid-loop reads.
// z unions with h2s (z only live after the last h2s read) -> 29.3 KB LDS.
// launch_bounds min-waves=4 (128-VGPR budget): R2's min=7 capped at 73 VGPR
// and spilled the loop state to scratch (WRITE_SIZE 12.5->130 MB). Occupancy
// is LDS-limited at 5 blocks/CU regardless.
__global__ __launch_bounds__(384, 4) void gather_kernel(
    const int* __restrict__ offsets,
    const int* __restrict__ srcs_csr,
    const float* __restrict__ y4csr,
    const __half* __restrict__ h2csr,      // (E,64) f16, CSR order, pre-scaled
    const __half* __restrict__ wtp_pack,   // B-fragment packed Wtp
    const float* __restrict__ feat_tbl,    // (N,320)
    const float* __restrict__ self_tbl,    // (N,320)
    const __half* __restrict__ wo_pack,    // f16 Wo0 (192x128) ++ Wo1 (192x64)
    float* __restrict__ out)               // (N,320)
{
    __shared__ __align__(16) __half wsh[CHUNK * 384];  // 24 KB
    __shared__ __align__(16) char pool[CHUNK * 128];   // 4 KB: h2s ∪ z
    __shared__ float ys[CHUNK][4];
    __shared__ int   srcs[CHUNK];
    __half* h2s = (__half*)pool;
    float*  z   = (float*)pool;                        // 768 floats, fits

    const int node = blockIdx.x;
    const int t = threadIdx.x;             // 0..383
    const int wave = t >> 6, lane = t & 63;
    const int quad = lane >> 4, n16 = lane & 15;

    const int beg = offsets[node], end = offsets[node + 1];

    // ---- prologue: issue chunk-0 staged loads immediately (longest chain) --
    int cb = beg;
    int ne = min(CHUNK, end - cb);
    half8 hreg = {};
    int   sreg = 0;
    float4 yreg = {0.f, 0.f, 0.f, 0.f};
    if (t < ne * 8) hreg = ((const half8*)(h2csr + (size_t)cb * 64))[t];
    if (t < ne)     { sreg = srcs_csr[cb + t]; yreg = ((const float4*)y4csr)[cb + t]; }

    // ---- B fragments (L2-hot, overlap the streaming loads above) ----
    half8 bf[4][2];
#pragma unroll
    for (int c = 0; c < 4; ++c) {
        const __half* p = wtp_pack + (size_t)((wave * 4 + c) * 64 + lane) * 16;
        bf[c][0] = *(const half8*)p;
        bf[c][1] = *(const half8*)(p + 8);
    }

    int f0;
    if (t < 128)      f0 = t;
    else if (t < 256) f0 = t - 128;
    else if (t < 320) f0 = 128 + 3 * (t - 256);
    else              f0 = 128 + 3 * (t - 320);

    float acc = 0.f, acc3a = 0.f, acc3b = 0.f, acc3c = 0.f;

    for (;;) {
        // ---- commit staged regs -> LDS ----
        if (t < ne) { srcs[t] = sreg; ((float4*)ys)[t] = yreg; }
        if (t < ne * 8) {                              // <=256 units, 1/thread
            const int eL = t >> 3, u = t & 7;
            *(half8*)((char*)h2s + eL * 128 + ((u * 16) ^ ((eL & 7) << 4))) = hreg;
        }
        __syncthreads();

        // ---- W = h2 @ Wtp via MFMA -> wsh (swizzled) ----
#pragma unroll
        for (int g = 0; g < 2; ++g) {
            if (g * 16 < ne) {                         // rows >= ne never read
                const int e = g * 16 + n16;
                const char* hb = (const char*)h2s + e * 128;
                const int sw = (e & 7) << 4;
                const half8 af0 = *(const half8*)(hb + ((quad * 16) ^ sw));
                const half8 af1 = *(const half8*)(hb + ((64 + quad * 16) ^ sw));
#pragma unroll
                for (int c = 0; c < 4; ++c) {
                    f32x4 acc4 = {0.f, 0.f, 0.f, 0.f};
                    acc4 = __builtin_amdgcn_mfma_f32_16x16x32_f16(af0, bf[c][0], acc4, 0, 0, 0);
                    acc4 = __builtin_amdgcn_mfma_f32_16x16x32_f16(af1, bf[c][1], acc4, 0, 0, 0);
                    const int colb = ((wave * 4 + c) * 16 + n16) * 2;
#pragma unroll
                    for (int r = 0; r < 4; ++r) {
                        const int row = g * 16 + quad * 4 + r;
                        *(__half*)((char*)wsh + row * 768 + (colb ^ (quad << 5))) =
                            (__half)acc4[r];
                    }
                }
            }
        }

        // ---- issue next-chunk staged loads (latency hidden under mid) ----
        const int cb2 = cb + CHUNK;
        const int ne2 = (cb2 < end) ? min(CHUNK, end - cb2) : 0;
        if (t < ne2 * 8) hreg = ((const half8*)(h2csr + (size_t)cb2 * 64))[t];
        if (t < ne2)     { sreg = srcs_csr[cb2 + t]; yreg = ((const float4*)y4csr)[cb2 + t]; }
        __syncthreads();   // wsh ready

        // ---- mid / aggregation (reads wsh with the row XOR) ----
        const int tb = t * 2;
        if (t < 128) {                       // A: mid0a
            for (int e = 0; e < ne; ++e) {
                const float w = __half2float(*(const __half*)(
                    (const char*)wsh + e * 768 + (tb ^ (((e >> 2) & 3) << 5))));
                const float* fr = feat_tbl + (size_t)srcs[e] * FEAT_W;
                acc += w * fr[f0] * ys[e][0];
            }
        } else if (t < 256) {                // B: mid1a
            for (int e = 0; e < ne; ++e) {
                const float w = __half2float(*(const __half*)(
                    (const char*)wsh + e * 768 + (tb ^ (((e >> 2) & 3) << 5))));
                const float* fr = feat_tbl + (size_t)srcs[e] * FEAT_W;
                const float p = w * fr[f0];
                acc3a += p * ys[e][1];
                acc3b += p * ys[e][2];
                acc3c += p * ys[e][3];
            }
        } else if (t < 320) {                // C: mid1b
            for (int e = 0; e < ne; ++e) {
                const float w = __half2float(*(const __half*)(
                    (const char*)wsh + e * 768 + (tb ^ (((e >> 2) & 3) << 5))));
                const float* fr = feat_tbl + (size_t)srcs[e] * FEAT_W;
                const float p = w * ys[e][0];
                acc3a += p * fr[f0];
                acc3b += p * fr[f0 + 1];
                acc3c += p * fr[f0 + 2];
            }
        } else {                             // D: mid0b
            for (int e = 0; e < ne; ++e) {
                const float w = __half2float(*(const __half*)(
                    (const char*)wsh + e * 768 + (tb ^ (((e >> 2) & 3) << 5))));
                const float* fr = feat_tbl + (size_t)srcs[e] * FEAT_W;
                const float d = fr[f0] * ys[e][1] + fr[f0 + 1] * ys[e][2]
                              + fr[f0 + 2] * ys[e][3];
                acc += w * d;
            }
        }

        if (!ne2) break;
        cb = cb2; ne = ne2;
        __syncthreads();   // protect wsh/h2s/srcs before overwrite
    }

    // ---- write z (aliases h2s; last h2s read was pre-mid-barrier) ----
    const float sZ = 0.25f;                  // 1/sqrt(16)
    if (t < 128) {
        z[t] = acc * sZ;
    } else if (t < 256) {
        const int u = t - 128;
        z[192 + 0 * 192 + u] = acc3a * sZ;
        z[192 + 1 * 192 + u] = acc3b * sZ;
        z[192 + 2 * 192 + u] = acc3c * sZ;
    } else if (t < 320) {
        const int u = t - 256;
        z[192 + 0 * 192 + 128 + u] = acc3a * sZ;
        z[192 + 1 * 192 + 128 + u] = acc3b * sZ;
        z[192 + 2 * 192 + 128 + u] = acc3c * sZ;
    } else {
        z[128 + (t - 320)] = acc * sZ * 0.5773502691896258f;  // mid0b, 1/sqrt(3)
    }
    __syncthreads();

    // ---- output GEMM (f16 Wo) + rotation combine ----
    const float sA = 0.07216878364870323f;   // 1/sqrt(192)
    const float cR = 0.92387953251128674f;   // cos(pi/8)
    const float sR = 0.38268343236508978f;   // sin(pi/8)
    const __half* Wo0h = wo_pack;            // 192x128
    const __half* Wo1h = wo_pack + 24576;    // 192x64

    if (t < 128) {
        float conv = 0.f;
        const float4* z4 = (const float4*)z;
#pragma unroll 8
        for (int q = 0; q < 48; ++q) {
            const float4 zz = z4[q];
            conv += zz.x * (float)Wo0h[(4 * q + 0) * 128 + t];
            conv += zz.y * (float)Wo0h[(4 * q + 1) * 128 + t];
            conv += zz.z * (float)Wo0h[(4 * q + 2) * 128 + t];
            conv += zz.w * (float)Wo0h[(4 * q + 3) * 128 + t];
        }
        const float sv = self_tbl[(size_t)node * FEAT_W + t];
        out[(size_t)node * FEAT_W + t] = cR * sv + sR * conv * sA;
    } else if (t < 320) {
        const int idx = t - 128;
        const int i = idx >> 6, u = idx & 63;
        float conv = 0.f;
        const float4* z4 = (const float4*)(z + 192 + i * 192);
#pragma unroll 8
        for (int q = 0; q < 48; ++q) {
            const float4 zz = z4[q];
            conv += zz.x * (float)Wo1h[(4 * q + 0) * 64 + u];
            conv += zz.y * (float)Wo1h[(4 * q + 1) * 64 + u];
            conv += zz.z * (float)Wo1h[(4 * q + 2) * 64 + u];
            conv += zz.w * (float)Wo1h[(4 * q + 3) * 64 + u];
        }
        const int col = 128 + u * 3 + i;
        const float sv = self_tbl[(size_t)node * FEAT_W + col];
        out[(size_t)node * FEAT_W + col] = cR * sv + sR * conv * sA;
    }
}

extern "C" void kernel_launch(void* const* d_in, const int* in_sizes, int n_in,
                              void* d_out, int out_size, void* d_ws, size_t ws_size,
                              hipStream_t stream) {
    const float* node_input = (const float*)d_in[0];
    const float* edge_attr  = (const float*)d_in[1];
    const float* esa        = (const float*)d_in[2];
    const float* Wa0  = (const float*)d_in[3];
    const float* Wa1  = (const float*)d_in[4];
    const float* Wb0  = (const float*)d_in[5];
    const float* Wb1  = (const float*)d_in[6];
    const float* M1   = (const float*)d_in[7];
    const float* M2   = (const float*)d_in[8];
    const float* Wtp0 = (const float*)d_in[9];
    const float* Wtp1 = (const float*)d_in[10];
    const float* Wtp2 = (const float*)d_in[11];
    const float* Wtp3 = (const float*)d_in[12];
    const float* Wo0  = (const float*)d_in[13];
    const float* Wo1  = (const float*)d_in[14];
    const int* edge_src = (const int*)d_in[15];
    const int* edge_dst = (const int*)d_in[16];
    float* out = (float*)d_out;

    // ws layout (~46 MB), 16B-aligned segments
    char* w = (char*)d_ws;
    float*  feat_tbl = (float*)w;           w += (size_t)N_NODES * FEAT_W * 4;
    float*  self_tbl = (float*)w;           w += (size_t)N_NODES * FEAT_W * 4;
    float*  y4csr    = (float*)w;           w += (size_t)N_EDGES * 4 * 4;
    __half* h2csr    = (__half*)w;          w += (size_t)N_EDGES * 64 * 2;
    __half* wtp_pack = (__half*)w;          w += (size_t)24576 * 2;
    __half* wo_pack  = (__half*)w;          w += (size_t)36864 * 2;
    int*    counts   = (int*)w;             w += (size_t)N_NODES * 4;
    int*    offsets  = (int*)w;             w += (size_t)(N_NODES + 1) * 4;
    int*    cursor   = (int*)w;             w += (size_t)N_NODES * 4;
    int*    srcs_csr = (int*)w;             w += (size_t)N_EDGES * 4;
    int*    pos_csr  = (int*)w;             w += (size_t)N_EDGES * 4;

    hipMemsetAsync(counts, 0, sizeof(int) * N_NODES, stream);

    count_kernel<<<N_EDGES / 256, 256, 0, stream>>>(edge_dst, counts);
    scan_kernel<<<1, 1024, 0, stream>>>(counts, offsets, cursor);
    fill_kernel<<<N_EDGES / 256, 256, 0, stream>>>(edge_dst, edge_src, edge_attr,
                                                   cursor, srcs_csr, y4csr, pos_csr);
    pack_weights<<<150, 256, 0, stream>>>(Wtp0, Wtp1, Wtp2, Wtp3, Wo0, Wo1,
                                          wtp_pack, wo_pack);
    node_transform<<<N_NODES / 8, 320, 0, stream>>>(node_input, Wa0, Wa1, Wb0, Wb1,
                                                    feat_tbl, self_tbl);
    mlp_kernel<<<N_EDGES / 4, 256, 0, stream>>>(esa, M1, M2, pos_csr, h2csr);
    gather_kernel<<<N_NODES, 384, 0, stream>>>(offsets, srcs_csr, y4csr, h2csr,
                                               wtp_pack, feat_tbl, self_tbl,
                                               wo_pack, out);
}

// Round 5
// 402.538 us; speedup vs baseline: 1.0582x; 1.0137x over previous
//
#include <hip/hip_runtime.h>
#include <hip/hip_bf16.h>
#include <hip/hip_fp16.h>

#define N_NODES 10000
#define N_EDGES 160000
#define FEAT_W 320
#define CHUNK 32

typedef _Float16 half8 __attribute__((ext_vector_type(8)));
typedef float f32x4 __attribute__((ext_vector_type(4)));

__device__ __forceinline__ float gelu_tanh(float x) {
    float x3 = x * x * x;
    float t = tanhf(0.7978845608028654f * (x + 0.044715f * x3));
    return 0.5f * x * (1.0f + t);
}

// ---------------- Kernel 1: node transforms, 8 nodes/block, fused feat+self -
__global__ __launch_bounds__(320) void node_transform(
    const float* __restrict__ node_input,
    const float* __restrict__ Wa0, const float* __restrict__ Wa1,
    const float* __restrict__ Wb0, const float* __restrict__ Wb1,
    float* __restrict__ feat_tbl, float* __restrict__ self_tbl)
{
    __shared__ __align__(16) float xT[FEAT_W][8];   // 10.24 KB
    const int node0 = blockIdx.x * 8;
    const int t = threadIdx.x;                      // 0..319 = output col
    for (int q = t; q < 640; q += 320) {            // 8 rows x 80 float4
        const int n = q / 80, c4 = q - n * 80;
        const float4 v = ((const float4*)(node_input + (size_t)(node0 + n) * FEAT_W))[c4];
        xT[c4 * 4 + 0][n] = v.x; xT[c4 * 4 + 1][n] = v.y;
        xT[c4 * 4 + 2][n] = v.z; xT[c4 * 4 + 3][n] = v.w;
    }
    __syncthreads();

    float accf[8] = {0,0,0,0,0,0,0,0}, accs[8] = {0,0,0,0,0,0,0,0};
    float scale;
    if (t < 128) {
        for (int v = 0; v < 128; ++v) {
            const float wa = Wa0[v * 128 + t];
            const float wb = Wb0[v * 128 + t];
            const float4 xa = *(const float4*)&xT[v][0];
            const float4 xb = *(const float4*)&xT[v][4];
            accf[0] += xa.x * wa; accf[1] += xa.y * wa; accf[2] += xa.z * wa; accf[3] += xa.w * wa;
            accf[4] += xb.x * wa; accf[5] += xb.y * wa; accf[6] += xb.z * wa; accf[7] += xb.w * wa;
            accs[0] += xa.x * wb; accs[1] += xa.y * wb; accs[2] += xa.z * wb; accs[3] += xa.w * wb;
            accs[4] += xb.x * wb; accs[5] += xb.y * wb; accs[6] += xb.z * wb; accs[7] += xb.w * wb;
        }
        scale = 0.08838834764831845f;               // 1/sqrt(128)
    } else {
        const int r = t - 128, u = r / 3, i = r - 3 * u;
        for (int v = 0; v < 64; ++v) {
            const float wa = Wa1[v * 64 + u];
            const float wb = Wb1[v * 64 + u];
            const int row = 128 + v * 3 + i;
            const float4 xa = *(const float4*)&xT[row][0];
            const float4 xb = *(const float4*)&xT[row][4];
            accf[0] += xa.x * wa; accf[1] += xa.y * wa; accf[2] += xa.z * wa; accf[3] += xa.w * wa;
            accf[4] += xb.x * wa; accf[5] += xb.y * wa; accf[6] += xb.z * wa; accf[7] += xb.w * wa;
            accs[0] += xa.x * wb; accs[1] += xa.y * wb; accs[2] += xa.z * wb; accs[3] += xa.w * wb;
            accs[4] += xb.x * wb; accs[5] += xb.y * wb; accs[6] += xb.z * wb; accs[7] += xb.w * wb;
        }
        scale = 0.125f;                             // 1/sqrt(64)
    }
#pragma unroll
    for (int n = 0; n < 8; ++n) {
        feat_tbl[(size_t)(node0 + n) * FEAT_W + t] = accf[n] * scale;
        self_tbl[(size_t)(node0 + n) * FEAT_W + t] = accs[n] * scale;
    }
}

// ---------------- count kernel (degrees) ------------------------------------
__global__ __launch_bounds__(256) void count_kernel(
    const int* __restrict__ edge_dst, int* __restrict__ counts)
{
    const int e = blockIdx.x * 256 + threadIdx.x;
    if (e < N_EDGES) atomicAdd(&counts[edge_dst[e]], 1);
}

// ---------------- CSR scan --------------------------------------------------
__global__ __launch_bounds__(1024) void scan_kernel(
    const int* __restrict__ counts, int* __restrict__ offsets, int* __restrict__ cursor)
{
    __shared__ int wsum[16];
    const int wid = threadIdx.x >> 6, lane = threadIdx.x & 63;
    int base = 0;
    for (int c = 0; c < 10; ++c) {            // 10*1024 >= 10000
        const int i = c * 1024 + threadIdx.x;
        const int v = (i < N_NODES) ? counts[i] : 0;
        int x = v;
#pragma unroll
        for (int off = 1; off < 64; off <<= 1) {
            int y = __shfl_up(x, off, 64);
            if (lane >= off) x += y;
        }
        if (lane == 63) wsum[wid] = x;
        __syncthreads();
        if (threadIdx.x < 16) {
            int s = wsum[threadIdx.x];
#pragma unroll
            for (int off = 1; off < 16; off <<= 1) {
                int y = __shfl_up(s, off, 64);
                if ((int)threadIdx.x >= off) s += y;
            }
            wsum[threadIdx.x] = s;
        }
        __syncthreads();
        const int waveoff = (wid == 0) ? 0 : wsum[wid - 1];
        const int excl = base + waveoff + x - v;
        if (i < N_NODES) { offsets[i] = excl; cursor[i] = excl; }
        const int tot = wsum[15];
        __syncthreads();
        base += tot;
    }
    if (threadIdx.x == 0) offsets[N_NODES] = base;
}

// fill: emits CSR-permuted src + y4 AND the edge->CSR-position map, so mlp
// can write h2 directly in CSR order (gather then streams it, no indirection).
__global__ void fill_kernel(const int* __restrict__ edge_dst,
                            const int* __restrict__ edge_src,
                            const float* __restrict__ edge_attr,
                            int* __restrict__ cursor,
                            int* __restrict__ srcs_csr, float* __restrict__ y4csr,
                            int* __restrict__ pos_csr) {
    int e = blockIdx.x * 256 + threadIdx.x;
    if (e < N_EDGES) {
        int pos = atomicAdd(&cursor[edge_dst[e]], 1);
        srcs_csr[pos] = edge_src[e];
        ((float4*)y4csr)[pos] = ((const float4*)edge_attr)[e];
        pos_csr[e] = pos;
    }
}

// ---------------- Kernel 2: per-edge MLP -> h2 f16, written in CSR order ----
__global__ __launch_bounds__(256) void mlp_kernel(
    const float* __restrict__ esa,   // (E,8)
    const float* __restrict__ M1,    // (8,64)
    const float* __restrict__ M2,    // (64,64)
    const int* __restrict__ pos_csr,
    __half* __restrict__ h2csr)      // (E,64) f16, CSR order, pre-scaled 1/8
{
    __shared__ __align__(16) float sh[4][64];
    const int wave = threadIdx.x >> 6;
    const int lane = threadIdx.x & 63;
    const int e = blockIdx.x * 4 + wave;   // N_EDGES % 4 == 0

    const int pos = pos_csr[e];            // issued early, latency hidden

    const float4 e0 = ((const float4*)(esa + (size_t)e * 8))[0];
    const float4 e1 = ((const float4*)(esa + (size_t)e * 8))[1];
    float h = e0.x * M1[0 * 64 + lane] + e0.y * M1[1 * 64 + lane]
            + e0.z * M1[2 * 64 + lane] + e0.w * M1[3 * 64 + lane]
            + e1.x * M1[4 * 64 + lane] + e1.y * M1[5 * 64 + lane]
            + e1.z * M1[6 * 64 + lane] + e1.w * M1[7 * 64 + lane];
    h = gelu_tanh(h * 0.35355339059327373f);   // 1/sqrt(8)
    sh[wave][lane] = h;
    __syncthreads();

    float h2 = 0.f;
    const float4* shp = (const float4*)sh[wave];
#pragma unroll
    for (int q = 0; q < 16; ++q) {
        const float4 s = shp[q];
        h2 += s.x * M2[(4 * q + 0) * 64 + lane];
        h2 += s.y * M2[(4 * q + 1) * 64 + lane];
        h2 += s.z * M2[(4 * q + 2) * 64 + lane];
        h2 += s.w * M2[(4 * q + 3) * 64 + lane];
    }
    h2 = gelu_tanh(h2 * 0.125f);               // 1/sqrt(64)
    h2csr[(size_t)pos * 64 + lane] = (__half)(h2 * 0.125f);  // fold 1/sqrt(64)
}

// ---------------- weight pre-pack (one-shot) --------------------------------
__global__ __launch_bounds__(256) void pack_weights(
    const float* __restrict__ Wtp0, const float* __restrict__ Wtp1,
    const float* __restrict__ Wtp2, const float* __restrict__ Wtp3,
    const float* __restrict__ Wo0,  const float* __restrict__ Wo1,
    __half* __restrict__ wtp_pack, __half* __restrict__ wo_pack)
{
    const int gid = blockIdx.x * 256 + threadIdx.x;   // 150*256 = 38400
    if (gid < 1536) {                                 // 24 tiles * 64 lanes
        const int lane = gid & 63;
        const int tile = gid >> 6;
        const int quad = lane >> 4, n16 = lane & 15;
        const int col = tile * 16 + n16;
        const float* src; int stride;
        if (col < 128)      { src = Wtp0 + col;         stride = 128; }
        else if (col < 256) { src = Wtp1 + (col - 128); stride = 128; }
        else if (col < 320) { src = Wtp2 + (col - 256); stride = 64;  }
        else                { src = Wtp3 + (col - 320); stride = 64;  }
        __half* dst = wtp_pack + (size_t)gid * 16;
#pragma unroll
        for (int s = 0; s < 2; ++s)
#pragma unroll
            for (int j = 0; j < 8; ++j)
                dst[s * 8 + j] = (__half)src[(s * 32 + quad * 8 + j) * stride];
    } else {
        const int i = gid - 1536;                     // 36864 = 192*128 + 192*64
        if (i < 24576) wo_pack[i] = (__half)Wo0[i];
        else           wo_pack[i] = (__half)Wo1[i - 24576];
    }
}

// ---------------- Kernel 3: fused W-proj (MFMA) + gather + out-GEMM ---------
// R3-verified structure (1 node/block). ONLY change vs R3: the mid loop is
// manually unrolled x4 with grouped, statically-indexed loads so 4 (A/B) or
// 12 (C/D) independent feat_tbl reads are in flight per wait, instead of a
// serial 1-load-per-edge dependent chain (R3 PMC: latency-bound, 16k cy/block
// vs 2k cy of work).
__global__ __launch_bounds__(384, 4) void gather_kernel(
    const int* __restrict__ offsets,
    const int* __restrict__ srcs_csr,
    const float* __restrict__ y4csr,
    const __half* __restrict__ h2csr,      // (E,64) f16, CSR order, pre-scaled
    const __half* __restrict__ wtp_pack,   // B-fragment packed Wtp
    const float* __restrict__ feat_tbl,    // (N,320)
    const float* __restrict__ self_tbl,    // (N,320)
    const __half* __restrict__ wo_pack,    // f16 Wo0 (192x128) ++ Wo1 (192x64)
    float* __restrict__ out)               // (N,320)
{
    __shared__ __align__(16) __half wsh[CHUNK * 384];  // 24 KB
    __shared__ __align__(16) char pool[CHUNK * 128];   // 4 KB: h2s ∪ z
    __shared__ float ys[CHUNK][4];
    __shared__ int   srcs[CHUNK];
    __half* h2s = (__half*)pool;
    float*  z   = (float*)pool;                        // 768 floats, fits

    const int node = blockIdx.x;
    const int t = threadIdx.x;             // 0..383
    const int wave = t >> 6, lane = t & 63;
    const int quad = lane >> 4, n16 = lane & 15;

    const int beg = offsets[node], end = offsets[node + 1];

    // ---- prologue: issue chunk-0 staged loads immediately (longest chain) --
    int cb = beg;
    int ne = min(CHUNK, end - cb);
    half8 hreg = {};
    int   sreg = 0;
    float4 yreg = {0.f, 0.f, 0.f, 0.f};
    if (t < ne * 8) hreg = ((const half8*)(h2csr + (size_t)cb * 64))[t];
    if (t < ne)     { sreg = srcs_csr[cb + t]; yreg = ((const float4*)y4csr)[cb + t]; }

    // ---- B fragments (L2-hot, overlap the streaming loads above) ----
    half8 bf[4][2];
#pragma unroll
    for (int c = 0; c < 4; ++c) {
        const __half* p = wtp_pack + (size_t)((wave * 4 + c) * 64 + lane) * 16;
        bf[c][0] = *(const half8*)p;
        bf[c][1] = *(const half8*)(p + 8);
    }

    int f0;
    if (t < 128)      f0 = t;
    else if (t < 256) f0 = t - 128;
    else if (t < 320) f0 = 128 + 3 * (t - 256);
    else              f0 = 128 + 3 * (t - 320);

    float acc = 0.f, acc3a = 0.f, acc3b = 0.f, acc3c = 0.f;

    for (;;) {
        // ---- commit staged regs -> LDS ----
        if (t < ne) { srcs[t] = sreg; ((float4*)ys)[t] = yreg; }
        if (t < ne * 8) {                              // <=256 units, 1/thread
            const int eL = t >> 3, u = t & 7;
            *(half8*)((char*)h2s + eL * 128 + ((u * 16) ^ ((eL & 7) << 4))) = hreg;
        }
        __syncthreads();

        // ---- W = h2 @ Wtp via MFMA -> wsh (swizzled) ----
#pragma unroll
        for (int g = 0; g < 2; ++g) {
            if (g * 16 < ne) {                         // rows >= ne never read
                const int e = g * 16 + n16;
                const char* hb = (const char*)h2s + e * 128;
                const int sw = (e & 7) << 4;
                const half8 af0 = *(const half8*)(hb + ((quad * 16) ^ sw));
                const half8 af1 = *(const half8*)(hb + ((64 + quad * 16) ^ sw));
#pragma unroll
                for (int c = 0; c < 4; ++c) {
                    f32x4 acc4 = {0.f, 0.f, 0.f, 0.f};
                    acc4 = __builtin_amdgcn_mfma_f32_16x16x32_f16(af0, bf[c][0], acc4, 0, 0, 0);
                    acc4 = __builtin_amdgcn_mfma_f32_16x16x32_f16(af1, bf[c][1], acc4, 0, 0, 0);
                    const int colb = ((wave * 4 + c) * 16 + n16) * 2;
#pragma unroll
                    for (int r = 0; r < 4; ++r) {
                        const int row = g * 16 + quad * 4 + r;
                        *(__half*)((char*)wsh + row * 768 + (colb ^ (quad << 5))) =
                            (__half)acc4[r];
                    }
                }
            }
        }

        // ---- issue next-chunk staged loads (latency hidden under mid) ----
        const int cb2 = cb + CHUNK;
        const int ne2 = (cb2 < end) ? min(CHUNK, end - cb2) : 0;
        if (t < ne2 * 8) hreg = ((const half8*)(h2csr + (size_t)cb2 * 64))[t];
        if (t < ne2)     { sreg = srcs_csr[cb2 + t]; yreg = ((const float4*)y4csr)[cb2 + t]; }
        __syncthreads();   // wsh ready

        // ---- mid / aggregation: x4 unrolled, grouped independent loads ----
        const int tb = t * 2;
#define WRD(ee) __half2float(*(const __half*)((const char*)wsh + (ee) * 768 + (tb ^ ((((ee) >> 2) & 3) << 5))))
        if (t < 128) {                       // A: mid0a
            int e = 0;
            for (; e + 4 <= ne; e += 4) {
                float w4[4], v4[4]; int s4[4];
#pragma unroll
                for (int k = 0; k < 4; ++k) { w4[k] = WRD(e + k); s4[k] = srcs[e + k]; }
#pragma unroll
                for (int k = 0; k < 4; ++k) v4[k] = feat_tbl[(size_t)s4[k] * FEAT_W + f0];
#pragma unroll
                for (int k = 0; k < 4; ++k) acc += w4[k] * v4[k] * ys[e + k][0];
            }
            for (; e < ne; ++e)
                acc += WRD(e) * feat_tbl[(size_t)srcs[e] * FEAT_W + f0] * ys[e][0];
        } else if (t < 256) {                // B: mid1a
            int e = 0;
            for (; e + 4 <= ne; e += 4) {
                float w4[4], v4[4]; int s4[4];
#pragma unroll
                for (int k = 0; k < 4; ++k) { w4[k] = WRD(e + k); s4[k] = srcs[e + k]; }
#pragma unroll
                for (int k = 0; k < 4; ++k) v4[k] = feat_tbl[(size_t)s4[k] * FEAT_W + f0];
#pragma unroll
                for (int k = 0; k < 4; ++k) {
                    const float p = w4[k] * v4[k];
                    a3aAdd: ;
                    acc3a += p * ys[e + k][1];
                    acc3b += p * ys[e + k][2];
                    acc3c += p * ys[e + k][3];
                }
            }
            for (; e < ne; ++e) {
                const float p = WRD(e) * feat_tbl[(size_t)srcs[e] * FEAT_W + f0];
                acc3a += p * ys[e][1]; acc3b += p * ys[e][2]; acc3c += p * ys[e][3];
            }
        } else if (t < 320) {                // C: mid1b
            int e = 0;
            for (; e + 4 <= ne; e += 4) {
                float w4[4], va[4], vb[4], vc[4]; int s4[4];
#pragma unroll
                for (int k = 0; k < 4; ++k) { w4[k] = WRD(e + k); s4[k] = srcs[e + k]; }
#pragma unroll
                for (int k = 0; k < 4; ++k) {
                    const float* fr = feat_tbl + (size_t)s4[k] * FEAT_W;
                    va[k] = fr[f0]; vb[k] = fr[f0 + 1]; vc[k] = fr[f0 + 2];
                }
#pragma unroll
                for (int k = 0; k < 4; ++k) {
                    const float p = w4[k] * ys[e + k][0];
                    acc3a += p * va[k]; acc3b += p * vb[k]; acc3c += p * vc[k];
                }
            }
            for (; e < ne; ++e) {
                const float* fr = feat_tbl + (size_t)srcs[e] * FEAT_W;
                const float p = WRD(e) * ys[e][0];
                acc3a += p * fr[f0]; acc3b += p * fr[f0 + 1]; acc3c += p * fr[f0 + 2];
            }
        } else {                             // D: mid0b
            int e = 0;
            for (; e + 4 <= ne; e += 4) {
                float w4[4], va[4], vb[4], vc[4]; int s4[4];
#pragma unroll
                for (int k = 0; k < 4; ++k) { w4[k] = WRD(e + k); s4[k] = srcs[e + k]; }
#pragma unroll
                for (int k = 0; k < 4; ++k) {
                    const float* fr = feat_tbl + (size_t)s4[k] * FEAT_W;
                    va[k] = fr[f0]; vb[k] = fr[f0 + 1]; vc[k] = fr[f0 + 2];
                }
#pragma unroll
                for (int k = 0; k < 4; ++k)
                    acc += w4[k] * (va[k] * ys[e + k][1] + vb[k] * ys[e + k][2]
                                  + vc[k] * ys[e + k][3]);
            }
            for (; e < ne; ++e) {
                const float* fr = feat_tbl + (size_t)srcs[e] * FEAT_W;
                acc += WRD(e) * (fr[f0] * ys[e][1] + fr[f0 + 1] * ys[e][2]
                               + fr[f0 + 2] * ys[e][3]);
            }
        }
#undef WRD

        if (!ne2) break;
        cb = cb2; ne = ne2;
        __syncthreads();   // protect wsh/h2s/srcs before overwrite
    }

    // ---- write z (aliases h2s; last h2s read was pre-mid-barrier) ----
    const float sZ = 0.25f;                  // 1/sqrt(16)
    if (t < 128) {
        z[t] = acc * sZ;
    } else if (t < 256) {
        const int u = t - 128;
        z[192 + 0 * 192 + u] = acc3a * sZ;
        z[192 + 1 * 192 + u] = acc3b * sZ;
        z[192 + 2 * 192 + u] = acc3c * sZ;
    } else if (t < 320) {
        const int u = t - 256;
        z[192 + 0 * 192 + 128 + u] = acc3a * sZ;
        z[192 + 1 * 192 + 128 + u] = acc3b * sZ;
        z[192 + 2 * 192 + 128 + u] = acc3c * sZ;
    } else {
        z[128 + (t - 320)] = acc * sZ * 0.5773502691896258f;  // mid0b, 1/sqrt(3)
    }
    __syncthreads();

    // ---- output GEMM (f16 Wo) + rotation combine ----
    const float sA = 0.07216878364870323f;   // 1/sqrt(192)
    const float cR = 0.92387953251128674f;   // cos(pi/8)
    const float sR = 0.38268343236508978f;   // sin(pi/8)
    const __half* Wo0h = wo_pack;            // 192x128
    const __half* Wo1h = wo_pack + 24576;    // 192x64

    if (t < 128) {
        float conv = 0.f;
        const float4* z4 = (const float4*)z;
#pragma unroll 8
        for (int q = 0; q < 48; ++q) {
            const float4 zz = z4[q];
            conv += zz.x * (float)Wo0h[(4 * q + 0) * 128 + t];
            conv += zz.y * (float)Wo0h[(4 * q + 1) * 128 + t];
            conv += zz.z * (float)Wo0h[(4 * q + 2) * 128 + t];
            conv += zz.w * (float)Wo0h[(4 * q + 3) * 128 + t];
        }
        const float sv = self_tbl[(size_t)node * FEAT_W + t];
        out[(size_t)node * FEAT_W + t] = cR * sv + sR * conv * sA;
    } else if (t < 320) {
        const int idx = t - 128;
        const int i = idx >> 6, u = idx & 63;
        float conv = 0.f;
        const float4* z4 = (const float4*)(z + 192 + i * 192);
#pragma unroll 8
        for (int q = 0; q < 48; ++q) {
            const float4 zz = z4[q];
            conv += zz.x * (float)Wo1h[(4 * q + 0) * 64 + u];
            conv += zz.y * (float)Wo1h[(4 * q + 1) * 64 + u];
            conv += zz.z * (float)Wo1h[(4 * q + 2) * 64 + u];
            conv += zz.w * (float)Wo1h[(4 * q + 3) * 64 + u];
        }
        const int col = 128 + u * 3 + i;
        const float sv = self_tbl[(size_t)node * FEAT_W + col];
        out[(size_t)node * FEAT_W + col] = cR * sv + sR * conv * sA;
    }
}

extern "C" void kernel_launch(void* const* d_in, const int* in_sizes, int n_in,
                              void* d_out, int out_size, void* d_ws, size_t ws_size,
                              hipStream_t stream) {
    const float* node_input = (const float*)d_in[0];
    const float* edge_attr  = (const float*)d_in[1];
    const float* esa        = (const float*)d_in[2];
    const float* Wa0  = (const float*)d_in[3];
    const float* Wa1  = (const float*)d_in[4];
    const float* Wb0  = (const float*)d_in[5];
    const float* Wb1  = (const float*)d_in[6];
    const float* M1   = (const float*)d_in[7];
    const float* M2   = (const float*)d_in[8];
    const float* Wtp0 = (const float*)d_in[9];
    const float* Wtp1 = (const float*)d_in[10];
    const float* Wtp2 = (const float*)d_in[11];
    const float* Wtp3 = (const float*)d_in[12];
    const float* Wo0  = (const float*)d_in[13];
    const float* Wo1  = (const float*)d_in[14];
    const int* edge_src = (const int*)d_in[15];
    const int* edge_dst = (const int*)d_in[16];
    float* out = (float*)d_out;

    // ws layout (~46 MB), 16B-aligned segments
    char* w = (char*)d_ws;
    float*  feat_tbl = (float*)w;           w += (size_t)N_NODES * FEAT_W * 4;
    float*  self_tbl = (float*)w;           w += (size_t)N_NODES * FEAT_W * 4;
    float*  y4csr    = (float*)w;           w += (size_t)N_EDGES * 4 * 4;
    __half* h2csr    = (__half*)w;          w += (size_t)N_EDGES * 64 * 2;
    __half* wtp_pack = (__half*)w;          w += (size_t)24576 * 2;
    __half* wo_pack  = (__half*)w;          w += (size_t)36864 * 2;
    int*    counts   = (int*)w;             w += (size_t)N_NODES * 4;
    int*    offsets  = (int*)w;             w += (size_t)(N_NODES + 1) * 4;
    int*    cursor   = (int*)w;             w += (size_t)N_NODES * 4;
    int*    srcs_csr = (int*)w;             w += (size_t)N_EDGES * 4;
    int*    pos_csr  = (int*)w;             w += (size_t)N_EDGES * 4;

    hipMemsetAsync(counts, 0, sizeof(int) * N_NODES, stream);

    count_kernel<<<N_EDGES / 256, 256, 0, stream>>>(edge_dst, counts);
    scan_kernel<<<1, 1024, 0, stream>>>(counts, offsets, cursor);
    fill_kernel<<<N_EDGES / 256, 256, 0, stream>>>(edge_dst, edge_src, edge_attr,
                                                   cursor, srcs_csr, y4csr, pos_csr);
    pack_weights<<<150, 256, 0, stream>>>(Wtp0, Wtp1, Wtp2, Wtp3, Wo0, Wo1,
                                          wtp_pack, wo_pack);
    node_transform<<<N_NODES / 8, 320, 0, stream>>>(node_input, Wa0, Wa1, Wb0, Wb1,
                                                    feat_tbl, self_tbl);
    mlp_kernel<<<N_EDGES / 4, 256, 0, stream>>>(esa, M1, M2, pos_csr, h2csr);
    gather_kernel<<<N_NODES, 384, 0, stream>>>(offsets, srcs_csr, y4csr, h2csr,
                                               wtp_pack, feat_tbl, self_tbl,
                                               wo_pack, out);
}